// Round 1
// baseline (1220.389 us; speedup 1.0000x reference)
//
#include <hip/hip_runtime.h>

// Problem constants (match reference setup_inputs)
static constexpr int M_ROWS = 100000;
static constexpr int N_IN   = 150000;
static constexpr int C_IN   = 32;
static constexpr int CO     = 64;
static constexpr float EPS  = 1e-5f;

// ---------------------------------------------------------------------------
// Gather-GEMM sparse conv: out[m, :] = sum_k feats[nbr[m,k], :] @ W[k]
// One thread computes 1 row x 4 output channels. 16 rows per block (256 thr).
// W[k] slab (CIN x 64) staged in LDS per tap.
// ---------------------------------------------------------------------------
template<int CIN, int KOFF, bool GATHER>
__global__ __launch_bounds__(256) void spconv_k(
    const float* __restrict__ feats,
    const int*   __restrict__ nbr,
    const float* __restrict__ W,
    float* __restrict__ out)
{
    __shared__ float Bs[CIN][CO];
    const int tid = threadIdx.x;
    const int co0 = (tid & 15) * 4;
    const int r   = tid >> 4;               // 0..15
    const int m   = blockIdx.x * 16 + r;    // M divisible by 16 (100000/16=6250)

    float a0 = 0.f, a1 = 0.f, a2 = 0.f, a3 = 0.f;

    for (int k = 0; k < KOFF; ++k) {
        // stage W[k] (CIN*CO floats) into LDS
        __syncthreads();
        {
            const float4* src = (const float4*)(W + (size_t)k * CIN * CO);
            float4* dst = (float4*)&Bs[0][0];
            #pragma unroll 1
            for (int i = tid; i < CIN * CO / 4; i += 256) dst[i] = src[i];
        }
        __syncthreads();

        int idx;
        if (GATHER) idx = nbr[m * KOFF + k];
        else        idx = m;
        if (idx >= 0) {
            const float* f = feats + (size_t)idx * CIN;
            #pragma unroll
            for (int c4 = 0; c4 < CIN / 4; ++c4) {
                float4 fv = *(const float4*)(f + c4 * 4);
                #pragma unroll
                for (int j = 0; j < 4; ++j) {
                    float fs = (j == 0) ? fv.x : (j == 1) ? fv.y : (j == 2) ? fv.z : fv.w;
                    float4 b = *(const float4*)&Bs[c4 * 4 + j][co0];
                    a0 += fs * b.x; a1 += fs * b.y; a2 += fs * b.z; a3 += fs * b.w;
                }
            }
        }
    }

    float4 v; v.x = a0; v.y = a1; v.z = a2; v.w = a3;
    *(float4*)(out + (size_t)m * CO + co0) = v;
}

// ---------------------------------------------------------------------------
// BN stats stage 1: per-block partial sum / sumsq per channel.
// part layout: [block][2][64]
// ---------------------------------------------------------------------------
__global__ __launch_bounds__(256) void bn_stats_partial(
    const float* __restrict__ y, float* __restrict__ part, int M)
{
    const int tid = threadIdx.x;
    const int c   = tid & 63;
    const int rg  = tid >> 6;   // 0..3
    const int nb  = gridDim.x;
    const int rows_per_block = (M + nb - 1) / nb;
    const int r0 = blockIdx.x * rows_per_block;
    const int r1 = min(M, r0 + rows_per_block);

    float s = 0.f, s2 = 0.f;
    for (int r = r0 + rg; r < r1; r += 4) {
        float v = y[(size_t)r * 64 + c];
        s += v; s2 += v * v;
    }
    __shared__ float sh[2][4][64];
    sh[0][rg][c] = s; sh[1][rg][c] = s2;
    __syncthreads();
    if (tid < 64) {
        float S  = sh[0][0][tid] + sh[0][1][tid] + sh[0][2][tid] + sh[0][3][tid];
        float S2 = sh[1][0][tid] + sh[1][1][tid] + sh[1][2][tid] + sh[1][3][tid];
        part[(size_t)blockIdx.x * 128 + tid]      = S;
        part[(size_t)blockIdx.x * 128 + 64 + tid] = S2;
    }
}

// ---------------------------------------------------------------------------
// BN stats stage 2: reduce partials -> per-channel scale/shift.
// ss[c] = g*rstd ; ss[64+c] = b - mean*g*rstd
// ---------------------------------------------------------------------------
__global__ __launch_bounds__(64) void bn_finalize(
    const float* __restrict__ part, int nblocks,
    const float* __restrict__ g, const float* __restrict__ b,
    float* __restrict__ ss, int M)
{
    const int c = threadIdx.x; // 64 threads
    float S = 0.f, S2 = 0.f;
    for (int i = 0; i < nblocks; ++i) {
        S  += part[(size_t)i * 128 + c];
        S2 += part[(size_t)i * 128 + 64 + c];
    }
    float mean = S / (float)M;
    float var  = S2 / (float)M - mean * mean;
    float rstd = rsqrtf(var + EPS);
    float sc = g[c] * rstd;
    ss[c]      = sc;
    ss[64 + c] = b[c] - mean * sc;
}

// ---------------------------------------------------------------------------
// BN apply (vectorized float4), optional residual add and ReLU.
// n4 = M*64/4 float4 elements.
// ---------------------------------------------------------------------------
__global__ __launch_bounds__(256) void bn_apply(
    const float* __restrict__ y, const float* __restrict__ ss,
    const float* __restrict__ res, float* __restrict__ out,
    int n4, int do_relu)
{
    for (int i = blockIdx.x * 256 + threadIdx.x; i < n4; i += gridDim.x * 256) {
        float4 v = ((const float4*)y)[i];
        int c0 = (i * 4) & 63;
        float4 sc = *(const float4*)(ss + c0);
        float4 sh = *(const float4*)(ss + 64 + c0);
        v.x = v.x * sc.x + sh.x;
        v.y = v.y * sc.y + sh.y;
        v.z = v.z * sc.z + sh.z;
        v.w = v.w * sc.w + sh.w;
        if (res) {
            float4 rv = ((const float4*)res)[i];
            v.x += rv.x; v.y += rv.y; v.z += rv.z; v.w += rv.w;
        }
        if (do_relu) {
            v.x = fmaxf(v.x, 0.f); v.y = fmaxf(v.y, 0.f);
            v.z = fmaxf(v.z, 0.f); v.w = fmaxf(v.w, 0.f);
        }
        ((float4*)out)[i] = v;
    }
}

// ---------------------------------------------------------------------------
extern "C" void kernel_launch(void* const* d_in, const int* in_sizes, int n_in,
                              void* d_out, int out_size, void* d_ws, size_t ws_size,
                              hipStream_t stream)
{
    const float* x_feats = (const float*)d_in[0];
    const float* w_down  = (const float*)d_in[1];
    const float* g_down  = (const float*)d_in[2];
    const float* b_down  = (const float*)d_in[3];
    const float* w_proj  = (const float*)d_in[4];
    const float* g_p     = (const float*)d_in[5];
    const float* b_p     = (const float*)d_in[6];
    const float* w1      = (const float*)d_in[7];
    const float* g1      = (const float*)d_in[8];
    const float* b1      = (const float*)d_in[9];
    const float* w2      = (const float*)d_in[10];
    const float* g2      = (const float*)d_in[11];
    const float* b2      = (const float*)d_in[12];
    const int*   nbr_down = (const int*)d_in[13];
    const int*   nbr_sub  = (const int*)d_in[14];
    float* out = (float*)d_out;

    const int M = M_ROWS;
    const size_t feat_elems = (size_t)M * CO;           // 6.4M floats
    char* ws = (char*)d_ws;
    float* bufX  = (float*)(ws);                         // 25.6 MB
    float* bufR  = (float*)(ws + feat_elems * 4);        // 25.6 MB
    float* bufZ  = (float*)(ws + feat_elems * 8);        // 25.6 MB
    float* part  = (float*)(ws + feat_elems * 12);       // 256*128*4 = 128 KB
    float* ss0   = (float*)(ws + feat_elems * 12 + 256 * 128 * 4);
    float* ss1   = ss0 + 128;
    float* ss2   = ss1 + 128;
    float* ss3   = ss2 + 128;

    const int conv_grid = M / 16;      // 6250
    const int stat_grid = 256;
    const int n4 = M * CO / 4;
    const int ew_grid = 2048;

    // 1) down conv: x_feats (N_IN x 32) -> bufX (M x 64)
    spconv_k<C_IN, 8, true><<<conv_grid, 256, 0, stream>>>(x_feats, nbr_down, w_down, bufX);
    bn_stats_partial<<<stat_grid, 256, 0, stream>>>(bufX, part, M);
    bn_finalize<<<1, 64, 0, stream>>>(part, stat_grid, g_down, b_down, ss0, M);
    bn_apply<<<ew_grid, 256, 0, stream>>>(bufX, ss0, nullptr, bufX, n4, 1);   // x = relu(bn(.))

    // 2) proj: res = bn(x @ w_proj)
    spconv_k<CO, 1, false><<<conv_grid, 256, 0, stream>>>(bufX, nullptr, w_proj, bufR);
    bn_stats_partial<<<stat_grid, 256, 0, stream>>>(bufR, part, M);
    bn_finalize<<<1, 64, 0, stream>>>(part, stat_grid, g_p, b_p, ss1, M);
    bn_apply<<<ew_grid, 256, 0, stream>>>(bufR, ss1, nullptr, bufR, n4, 0);

    // 3) conv1: z = relu(bn(spconv(x, nbr_sub, w1)))
    spconv_k<CO, 27, true><<<conv_grid, 256, 0, stream>>>(bufX, nbr_sub, w1, bufZ);
    bn_stats_partial<<<stat_grid, 256, 0, stream>>>(bufZ, part, M);
    bn_finalize<<<1, 64, 0, stream>>>(part, stat_grid, g1, b1, ss2, M);
    bn_apply<<<ew_grid, 256, 0, stream>>>(bufZ, ss2, nullptr, bufZ, n4, 1);

    // 4) conv2: out = relu(bn(spconv(z, nbr_sub, w2)) + res)
    spconv_k<CO, 27, true><<<conv_grid, 256, 0, stream>>>(bufZ, nbr_sub, w2, out);
    bn_stats_partial<<<stat_grid, 256, 0, stream>>>(out, part, M);
    bn_finalize<<<1, 64, 0, stream>>>(part, stat_grid, g2, b2, ss3, M);
    bn_apply<<<ew_grid, 256, 0, stream>>>(out, ss3, bufR, out, n4, 1);
}

// Round 2
// 827.156 us; speedup vs baseline: 1.4754x; 1.4754x over previous
//
#include <hip/hip_runtime.h>

// Problem constants (match reference setup_inputs)
static constexpr int M_ROWS = 100000;
static constexpr int N_IN   = 150000;
static constexpr int C_IN   = 32;
static constexpr int CO     = 64;
static constexpr float EPS  = 1e-5f;

typedef __bf16 bf16x8 __attribute__((ext_vector_type(8)));
typedef float  f32x4  __attribute__((ext_vector_type(4)));
typedef unsigned short u16x8 __attribute__((ext_vector_type(8)));
typedef short  short8 __attribute__((ext_vector_type(8)));

static __device__ __forceinline__ unsigned short f2bf(float f) {
    unsigned int u = __builtin_bit_cast(unsigned int, f);
    u += 0x7fff + ((u >> 16) & 1);              // round-to-nearest-even
    return (unsigned short)(u >> 16);
}

// ---------------------------------------------------------------------------
// f32 -> bf16 elementwise cast (8 elems/thread)
// ---------------------------------------------------------------------------
__global__ __launch_bounds__(256) void cvt_bf16(
    const float* __restrict__ in, unsigned short* __restrict__ out, int n8)
{
    int i = blockIdx.x * 256 + threadIdx.x;
    if (i >= n8) return;
    float4 a = ((const float4*)in)[2 * i];
    float4 b = ((const float4*)in)[2 * i + 1];
    u16x8 v;
    v[0] = f2bf(a.x); v[1] = f2bf(a.y); v[2] = f2bf(a.z); v[3] = f2bf(a.w);
    v[4] = f2bf(b.x); v[5] = f2bf(b.y); v[6] = f2bf(b.z); v[7] = f2bf(b.w);
    ((u16x8*)out)[i] = v;
}

// ---------------------------------------------------------------------------
// Weight cast+transpose: W [K][CIN][64] f32 -> WT [K][64][CIN] bf16
// ---------------------------------------------------------------------------
__global__ __launch_bounds__(256) void wt_cvt(
    const float* __restrict__ W, unsigned short* __restrict__ WT, int total, int cin)
{
    int t = blockIdx.x * 256 + threadIdx.x;
    if (t >= total) return;
    int k  = t / (cin * 64);
    int r  = t - k * (cin * 64);
    int ci = r >> 6;
    int co = r & 63;
    WT[((size_t)k * 64 + co) * cin + ci] = f2bf(W[t]);
}

// ---------------------------------------------------------------------------
// MFMA gather-conv: out[m,:] = sum_k featsB[nbr[m,k],:] @ W[k]   (f32 out)
// Block = 4 waves x 16 rows = 64 rows. Each wave: 16 rows x 64 cols via
// 4 N-tiles of mfma_f32_16x16x32_bf16, K-steps = CIN/32.
// A-fragments gathered per-lane from global bf16; B from pre-transposed WT.
// ---------------------------------------------------------------------------
template<int CIN, int KOFF, bool GATHER>
__global__ __launch_bounds__(256) void spconv_mfma(
    const unsigned short* __restrict__ fB,
    const int*   __restrict__ nbr,
    const unsigned short* __restrict__ WT,
    float* __restrict__ out)
{
    constexpr int KS = CIN / 32;
    const int lane = threadIdx.x & 63;
    const int wv   = threadIdx.x >> 6;
    const int m0   = blockIdx.x * 64 + wv * 16;
    const int rrow = m0 + (lane & 15);
    const bool rvalid = rrow < M_ROWS;
    const int kgrp = lane >> 4;          // 0..3
    const int colb = lane & 15;

    short8 zs = {0,0,0,0,0,0,0,0};
    const bf16x8 zf = __builtin_bit_cast(bf16x8, zs);

    f32x4 acc[4] = {};

    for (int k = 0; k < KOFF; ++k) {
        int idx;
        if (GATHER) idx = rvalid ? nbr[(size_t)rrow * KOFF + k] : -1;
        else        idx = rvalid ? rrow : -1;

        bf16x8 a[KS];
        #pragma unroll
        for (int s = 0; s < KS; ++s) a[s] = zf;
        if (idx >= 0) {
            const unsigned short* fp = fB + (size_t)idx * CIN + kgrp * 8;
            #pragma unroll
            for (int s = 0; s < KS; ++s)
                a[s] = *reinterpret_cast<const bf16x8*>(fp + s * 32);
        }

        const unsigned short* wp = WT + (size_t)k * 64 * CIN + kgrp * 8;
        #pragma unroll
        for (int n = 0; n < 4; ++n) {
            const unsigned short* wc = wp + (size_t)(n * 16 + colb) * CIN;
            #pragma unroll
            for (int s = 0; s < KS; ++s) {
                bf16x8 b = *reinterpret_cast<const bf16x8*>(wc + s * 32);
                acc[n] = __builtin_amdgcn_mfma_f32_16x16x32_bf16(a[s], b, acc[n], 0, 0, 0);
            }
        }
    }

    // C/D layout: col = lane&15, row = (lane>>4)*4 + j   [measured m89/m91]
    const int rbase = m0 + kgrp * 4;
    #pragma unroll
    for (int j = 0; j < 4; ++j) {
        int row = rbase + j;
        if (row < M_ROWS) {
            #pragma unroll
            for (int n = 0; n < 4; ++n)
                out[(size_t)row * 64 + n * 16 + colb] = acc[n][j];
        }
    }
}

// ---------------------------------------------------------------------------
// BN stats stage 1: per-block partial sum / sumsq per channel.
// ---------------------------------------------------------------------------
__global__ __launch_bounds__(256) void bn_stats_partial(
    const float* __restrict__ y, float* __restrict__ part, int M)
{
    const int tid = threadIdx.x;
    const int c   = tid & 63;
    const int rg  = tid >> 6;
    const int nb  = gridDim.x;
    const int rows_per_block = (M + nb - 1) / nb;
    const int r0 = blockIdx.x * rows_per_block;
    const int r1 = min(M, r0 + rows_per_block);

    float s = 0.f, s2 = 0.f;
    for (int r = r0 + rg; r < r1; r += 4) {
        float v = y[(size_t)r * 64 + c];
        s += v; s2 += v * v;
    }
    __shared__ float sh[2][4][64];
    sh[0][rg][c] = s; sh[1][rg][c] = s2;
    __syncthreads();
    if (tid < 64) {
        float S  = sh[0][0][tid] + sh[0][1][tid] + sh[0][2][tid] + sh[0][3][tid];
        float S2 = sh[1][0][tid] + sh[1][1][tid] + sh[1][2][tid] + sh[1][3][tid];
        part[(size_t)blockIdx.x * 128 + tid]      = S;
        part[(size_t)blockIdx.x * 128 + 64 + tid] = S2;
    }
}

__global__ __launch_bounds__(64) void bn_finalize(
    const float* __restrict__ part, int nblocks,
    const float* __restrict__ g, const float* __restrict__ b,
    float* __restrict__ ss, int M)
{
    const int c = threadIdx.x;
    float S = 0.f, S2 = 0.f;
    for (int i = 0; i < nblocks; ++i) {
        S  += part[(size_t)i * 128 + c];
        S2 += part[(size_t)i * 128 + 64 + c];
    }
    float mean = S / (float)M;
    float var  = S2 / (float)M - mean * mean;
    float rstd = rsqrtf(var + EPS);
    float sc = g[c] * rstd;
    ss[c]      = sc;
    ss[64 + c] = b[c] - mean * sc;
}

// ---------------------------------------------------------------------------
// BN apply, 8 channels/thread. BF16OUT writes bf16 (conv input for next op),
// else f32. Optional residual (f32) and ReLU.
// ---------------------------------------------------------------------------
template<bool BF16OUT, bool RES, bool RELU>
__global__ __launch_bounds__(256) void bn_apply(
    const float* __restrict__ y, const float* __restrict__ ss,
    const float* __restrict__ res, void* __restrict__ out, int n8)
{
    for (int i = blockIdx.x * 256 + threadIdx.x; i < n8; i += gridDim.x * 256) {
        float4 a = ((const float4*)y)[2 * i];
        float4 b = ((const float4*)y)[2 * i + 1];
        int c0 = (i * 8) & 63;
        float4 sca = *(const float4*)(ss + c0);
        float4 scb = *(const float4*)(ss + c0 + 4);
        float4 sha = *(const float4*)(ss + 64 + c0);
        float4 shb = *(const float4*)(ss + 64 + c0 + 4);
        float v[8];
        v[0] = a.x * sca.x + sha.x; v[1] = a.y * sca.y + sha.y;
        v[2] = a.z * sca.z + sha.z; v[3] = a.w * sca.w + sha.w;
        v[4] = b.x * scb.x + shb.x; v[5] = b.y * scb.y + shb.y;
        v[6] = b.z * scb.z + shb.z; v[7] = b.w * scb.w + shb.w;
        if (RES) {
            float4 ra = ((const float4*)res)[2 * i];
            float4 rb = ((const float4*)res)[2 * i + 1];
            v[0] += ra.x; v[1] += ra.y; v[2] += ra.z; v[3] += ra.w;
            v[4] += rb.x; v[5] += rb.y; v[6] += rb.z; v[7] += rb.w;
        }
        if (RELU) {
            #pragma unroll
            for (int j = 0; j < 8; ++j) v[j] = fmaxf(v[j], 0.f);
        }
        if (BF16OUT) {
            u16x8 o;
            #pragma unroll
            for (int j = 0; j < 8; ++j) o[j] = f2bf(v[j]);
            ((u16x8*)out)[i] = o;
        } else {
            float4 oa, ob;
            oa.x = v[0]; oa.y = v[1]; oa.z = v[2]; oa.w = v[3];
            ob.x = v[4]; ob.y = v[5]; ob.z = v[6]; ob.w = v[7];
            ((float4*)out)[2 * i]     = oa;
            ((float4*)out)[2 * i + 1] = ob;
        }
    }
}

// ---------------------------------------------------------------------------
extern "C" void kernel_launch(void* const* d_in, const int* in_sizes, int n_in,
                              void* d_out, int out_size, void* d_ws, size_t ws_size,
                              hipStream_t stream)
{
    const float* x_feats = (const float*)d_in[0];
    const float* w_down  = (const float*)d_in[1];
    const float* g_down  = (const float*)d_in[2];
    const float* b_down  = (const float*)d_in[3];
    const float* w_proj  = (const float*)d_in[4];
    const float* g_p     = (const float*)d_in[5];
    const float* b_p     = (const float*)d_in[6];
    const float* w1      = (const float*)d_in[7];
    const float* g1      = (const float*)d_in[8];
    const float* b1      = (const float*)d_in[9];
    const float* w2      = (const float*)d_in[10];
    const float* g2      = (const float*)d_in[11];
    const float* b2      = (const float*)d_in[12];
    const int*   nbr_down = (const int*)d_in[13];
    const int*   nbr_sub  = (const int*)d_in[14];
    float* out = (float*)d_out;

    const int M = M_ROWS;
    const size_t feat4 = (size_t)M * CO * 4;   // 25.6 MB f32
    const size_t feat2 = (size_t)M * CO * 2;   // 12.8 MB bf16
    auto align = [](size_t x) { return (x + 255) & ~(size_t)255; };

    char* ws = (char*)d_ws;
    size_t off = 0;
    unsigned short* xin16 = (unsigned short*)(ws + off); off += align((size_t)N_IN * C_IN * 2);
    unsigned short* wdT   = (unsigned short*)(ws + off); off += align((size_t)8 * CO * C_IN * 2);
    unsigned short* wpT   = (unsigned short*)(ws + off); off += align((size_t)1 * CO * CO * 2);
    unsigned short* w1T   = (unsigned short*)(ws + off); off += align((size_t)27 * CO * CO * 2);
    unsigned short* w2T   = (unsigned short*)(ws + off); off += align((size_t)27 * CO * CO * 2);
    float* Y    = (float*)(ws + off); off += align(feat4);
    float* bufR = (float*)(ws + off); off += align(feat4);
    unsigned short* xB = (unsigned short*)(ws + off); off += align(feat2);
    unsigned short* zB = (unsigned short*)(ws + off); off += align(feat2);
    float* part = (float*)(ws + off); off += align((size_t)256 * 128 * 4);
    float* ss0  = (float*)(ws + off);
    float* ss1  = ss0 + 128;
    float* ss2  = ss1 + 128;
    float* ss3  = ss2 + 128;

    const int conv_grid = (M + 63) / 64;   // 1563
    const int stat_grid = 256;
    const int n8 = M * CO / 8;             // 800000
    const int ew_grid = 2048;

    // 0) input + weight casts
    {
        int nf8 = N_IN * C_IN / 8;
        cvt_bf16<<<(nf8 + 255) / 256, 256, 0, stream>>>(x_feats, xin16, nf8);
        int t;
        t = 8 * C_IN * CO;  wt_cvt<<<(t + 255) / 256, 256, 0, stream>>>(w_down, wdT, t, C_IN);
        t = CO * CO;        wt_cvt<<<(t + 255) / 256, 256, 0, stream>>>(w_proj, wpT, t, CO);
        t = 27 * CO * CO;   wt_cvt<<<(t + 255) / 256, 256, 0, stream>>>(w1, w1T, t, CO);
        t = 27 * CO * CO;   wt_cvt<<<(t + 255) / 256, 256, 0, stream>>>(w2, w2T, t, CO);
    }

    // 1) down conv -> Y; x = relu(bn(Y)) -> xB (bf16)
    spconv_mfma<C_IN, 8, true><<<conv_grid, 256, 0, stream>>>(xin16, nbr_down, wdT, Y);
    bn_stats_partial<<<stat_grid, 256, 0, stream>>>(Y, part, M);
    bn_finalize<<<1, 64, 0, stream>>>(part, stat_grid, g_down, b_down, ss0, M);
    bn_apply<true, false, true><<<ew_grid, 256, 0, stream>>>(Y, ss0, nullptr, xB, n8);

    // 2) proj: res = bn(x @ w_proj) -> bufR (f32)
    spconv_mfma<CO, 1, false><<<conv_grid, 256, 0, stream>>>(xB, nullptr, wpT, Y);
    bn_stats_partial<<<stat_grid, 256, 0, stream>>>(Y, part, M);
    bn_finalize<<<1, 64, 0, stream>>>(part, stat_grid, g_p, b_p, ss1, M);
    bn_apply<false, false, false><<<ew_grid, 256, 0, stream>>>(Y, ss1, nullptr, bufR, n8);

    // 3) conv1: z = relu(bn(spconv(x, nbr_sub, w1))) -> zB (bf16)
    spconv_mfma<CO, 27, true><<<conv_grid, 256, 0, stream>>>(xB, nbr_sub, w1T, Y);
    bn_stats_partial<<<stat_grid, 256, 0, stream>>>(Y, part, M);
    bn_finalize<<<1, 64, 0, stream>>>(part, stat_grid, g1, b1, ss2, M);
    bn_apply<true, false, true><<<ew_grid, 256, 0, stream>>>(Y, ss2, nullptr, zB, n8);

    // 4) conv2: out = relu(bn(spconv(z, nbr_sub, w2)) + res)
    spconv_mfma<CO, 27, true><<<conv_grid, 256, 0, stream>>>(zB, nbr_sub, w2T, Y);
    bn_stats_partial<<<stat_grid, 256, 0, stream>>>(Y, part, M);
    bn_finalize<<<1, 64, 0, stream>>>(part, stat_grid, g2, b2, ss3, M);
    bn_apply<false, true, true><<<ew_grid, 256, 0, stream>>>(Y, ss3, bufR, out, n8);
}